// Round 5
// baseline (1614.391 us; speedup 1.0000x reference)
//
#include <hip/hip_runtime.h>

#define NN 8192
#define DD 256
#define ALPHA 50.0f
#define BETA 1.0f
#define THR 8.0f

typedef __attribute__((ext_vector_type(8))) short short8;
typedef __attribute__((ext_vector_type(4))) float f32x4;

static __device__ __forceinline__ ushort f2bf(float f) {
    union { float f; unsigned u; } v; v.f = f;
    unsigned u = v.u;
    return (ushort)((u + 0x7fffu + ((u >> 16) & 1u)) >> 16);
}

// --- W f32 -> bf16, once ---
__global__ void k_wconv(const float* __restrict__ W, ushort* __restrict__ Wb) {
    int i = blockIdx.x * 256 + threadIdx.x;
    Wb[i] = f2bf(W[i]);
}

// --- bitpack mask: bits[row][col/32], bit c = (sim[row][col] != 0) ---
__global__ __launch_bounds__(256) void k_pack(const float* __restrict__ sim,
                                              unsigned* __restrict__ bits) {
    int row = blockIdx.x;
    int w = threadIdx.x >> 6;
    int lane = threadIdx.x & 63;
    for (int p = 0; p < 32; ++p) {
        int col = p * 256 + w * 64 + lane;
        float v = sim[(size_t)row * NN + col];
        unsigned long long b = __ballot(v != 0.0f);
        if (lane == 0) {
            bits[row * (NN / 32) + p * 8 + w * 2]     = (unsigned)b;
            bits[row * (NN / 32) + p * 8 + w * 2 + 1] = (unsigned)(b >> 32);
        }
    }
}

// --- H f32 -> Hv bf16 (row-major) and Hvt bf16 (transposed [D][N]) ---
__global__ __launch_bounds__(256) void k_convert(const float* __restrict__ H,
                                                 ushort* __restrict__ Hv,
                                                 ushort* __restrict__ Hvt) {
    __shared__ ushort T[64][72];  // padded
    int tile = blockIdx.x;                  // 128 row-tiles * 4 col-tiles
    int r0 = (tile >> 2) * 64;
    int c0 = (tile & 3) * 64;
    int tid = threadIdx.x;
    int tr = tid >> 4;            // 0..15
    int tc = (tid & 15) * 4;      // 0..60
    for (int i = 0; i < 4; ++i) {
        int r = tr + i * 16;
        float4 v = *reinterpret_cast<const float4*>(H + (size_t)(r0 + r) * DD + c0 + tc);
        ushort4 o;
        o.x = f2bf(v.x); o.y = f2bf(v.y); o.z = f2bf(v.z); o.w = f2bf(v.w);
        *reinterpret_cast<ushort4*>(Hv + (size_t)(r0 + r) * DD + c0 + tc) = o;
        T[tc + 0][r] = o.x; T[tc + 1][r] = o.y; T[tc + 2][r] = o.z; T[tc + 3][r] = o.w;
    }
    __syncthreads();
    for (int i = 0; i < 4; ++i) {
        int c = tr + i * 16;      // local col -> global row of Hvt
        ushort4 o;
        o.x = T[c][tc + 0]; o.y = T[c][tc + 1]; o.z = T[c][tc + 2]; o.w = T[c][tc + 3];
        *reinterpret_cast<ushort4*>(Hvt + (size_t)(c0 + c) * NN + r0 + tc) = o;
    }
}

// --- Hp = bf16(Hv @ W^T + b) via MFMA ---
__global__ __launch_bounds__(256) void k_proj(const ushort* __restrict__ Hv,
                                              const ushort* __restrict__ Wb,
                                              const float* __restrict__ b,
                                              ushort* __restrict__ Hp) {
    int w = threadIdx.x >> 6;
    int lane = threadIdx.x & 63;
    int row0 = blockIdx.x * 64 + w * 16;
    int lr = lane & 15;
    int lk = lane >> 4;
    short8 af[8];
    for (int kk = 0; kk < 8; ++kk)
        af[kk] = *reinterpret_cast<const short8*>(Hv + (size_t)(row0 + lr) * DD + kk * 32 + lk * 8);
    for (int t = 0; t < 16; ++t) {
        f32x4 acc = {0.f, 0.f, 0.f, 0.f};
        int col = t * 16 + lr;
        for (int kk = 0; kk < 8; ++kk) {
            short8 bf = *reinterpret_cast<const short8*>(Wb + (size_t)col * DD + kk * 32 + lk * 8);
            acc = __builtin_amdgcn_mfma_f32_16x16x32_bf16(af[kk], bf, acc, 0, 0, 0);
        }
        float bias = b[col];
        for (int j = 0; j < 4; ++j) {
            int row = row0 + lk * 4 + j;
            Hp[(size_t)row * DD + col] = f2bf(acc[j] + bias);
        }
    }
}

// --- fused masked flash attention + CRF update ---
// grid = N/16 blocks, 512 threads (8 waves).
// wave w: kq = w&3 -> keys [kq*2048, +2048); dh = w>>2 -> cols [dh*128, +128).
// Bitpacked mask; defer-max; l via ones-column MFMA; V prefetched split 4+4.
__global__ __launch_bounds__(512, 4) void k_attn(const ushort* __restrict__ Hp,
                                                 const ushort* __restrict__ Hvt,
                                                 const unsigned* __restrict__ bits,
                                                 const float* __restrict__ Qo,
                                                 ushort* __restrict__ HvOut,
                                                 ushort* __restrict__ HvtOut,
                                                 float* __restrict__ Fout) {
    __shared__ ushort Plds[8][16][36];  // per-wave private P tile; 36: bank decorrelation
    __shared__ float Osum[16][257];     // merge buffer (+1 pad)
    __shared__ float Msh[4][16];
    __shared__ float Lsh[4][16];
    __shared__ float Lrow[16];

    const int tid = threadIdx.x;
    const int w   = tid >> 6;
    const int kq  = w & 3;
    const int dh  = w >> 2;
    const int lane = tid & 63;
    const int lr  = lane & 15;
    const int lk  = lane >> 4;
    const int q0  = blockIdx.x * 16;
    const int dbase = dh * 128;

    for (int i = tid; i < 16 * 257; i += 512) (&Osum[0][0])[i] = 0.f;

    short8 qf[8];
#pragma unroll
    for (int kk = 0; kk < 8; ++kk)
        qf[kk] = *reinterpret_cast<const short8*>(Hp + (size_t)(q0 + lr) * DD + kk * 32 + lk * 8);

    f32x4 o[8];
#pragma unroll
    for (int t = 0; t < 8; ++t) o[t] = {0.f, 0.f, 0.f, 0.f};
    f32x4 ol = {0.f, 0.f, 0.f, 0.f};
    float m[4] = {-1e30f, -1e30f, -1e30f, -1e30f};

    short8 ones;
#pragma unroll
    for (int e = 0; e < 8; ++e) ones[e] = (short)0x3f80;  // bf16 1.0

    const int rowbase = (q0 + lk * 4) * (NN / 32);
    const int kstart = kq * (NN / 4);
    for (int step = 0; step < (NN / 4) / 32; ++step) {
        const int kb = kstart + step * 32;
        const int wi = kb >> 5;
        // mask words (broadcast, issued first)
        unsigned mwj[4];
#pragma unroll
        for (int j = 0; j < 4; ++j) mwj[j] = bits[rowbase + j * (NN / 32) + wi];
        // V prefetch, first half (in flight across QK^T + softmax)
        short8 pv0[4];
#pragma unroll
        for (int tt = 0; tt < 4; ++tt)
            pv0[tt] = *reinterpret_cast<const short8*>(Hvt + (size_t)(dbase + tt * 16 + lr) * NN + kb + lk * 8);

        f32x4 s0 = {0.f, 0.f, 0.f, 0.f}, s1 = {0.f, 0.f, 0.f, 0.f};
#pragma unroll
        for (int kk = 0; kk < 8; ++kk) {
            short8 k0 = *reinterpret_cast<const short8*>(Hp + (size_t)(kb + lr) * DD + kk * 32 + lk * 8);
            short8 k1 = *reinterpret_cast<const short8*>(Hp + (size_t)(kb + 16 + lr) * DD + kk * 32 + lk * 8);
            s0 = __builtin_amdgcn_mfma_f32_16x16x32_bf16(qf[kk], k0, s0, 0, 0, 0);
            s1 = __builtin_amdgcn_mfma_f32_16x16x32_bf16(qf[kk], k1, s1, 0, 0, 0);
        }
        // mask + defer-max check (no shuffles on light path)
        float c = -1e30f;
#pragma unroll
        for (int j = 0; j < 4; ++j) {
            float a0 = ((mwj[j] >> lr) & 1u) ? s0[j] : -1e30f;
            float a1 = ((mwj[j] >> (lr + 16)) & 1u) ? s1[j] : -1e30f;
            s0[j] = a0; s1[j] = a1;
            c = fmaxf(c, fmaxf(a0, a1) - m[j]);
        }
        if (__any(c > THR)) {   // rare: new-max rescale
#pragma unroll
            for (int j = 0; j < 4; ++j) {
                float mx = fmaxf(s0[j], s1[j]);
                mx = fmaxf(mx, __shfl_xor(mx, 1));
                mx = fmaxf(mx, __shfl_xor(mx, 2));
                mx = fmaxf(mx, __shfl_xor(mx, 4));
                mx = fmaxf(mx, __shfl_xor(mx, 8));
                float mn = fmaxf(m[j], mx);
                float scale = __expf(m[j] - mn);
                m[j] = mn;
#pragma unroll
                for (int t = 0; t < 8; ++t) o[t][j] *= scale;
                ol[j] *= scale;
            }
        }
        // P -> LDS (wave-private; masked entries underflow to 0; all-masked-so-far
        // junk exp(0)=1 wiped by scale=0 at the row's first real max)
#pragma unroll
        for (int j = 0; j < 4; ++j) {
            Plds[w][lk * 4 + j][lr]      = f2bf(__expf(s0[j] - m[j]));
            Plds[w][lk * 4 + j][16 + lr] = f2bf(__expf(s1[j] - m[j]));
        }
        // V prefetch, second half (in flight across LDS drain)
        short8 pv1[4];
#pragma unroll
        for (int tt = 0; tt < 4; ++tt)
            pv1[tt] = *reinterpret_cast<const short8*>(Hvt + (size_t)(dbase + (4 + tt) * 16 + lr) * NN + kb + lk * 8);
        asm volatile("s_waitcnt lgkmcnt(0)" ::: "memory");
        __builtin_amdgcn_sched_barrier(0);
        short8 pa = *reinterpret_cast<const short8*>(&Plds[w][lr][lk * 8]);
        // O += P @ V ; l-sum via ones column
#pragma unroll
        for (int tt = 0; tt < 4; ++tt)
            o[tt] = __builtin_amdgcn_mfma_f32_16x16x32_bf16(pa, pv0[tt], o[tt], 0, 0, 0);
#pragma unroll
        for (int tt = 0; tt < 4; ++tt)
            o[4 + tt] = __builtin_amdgcn_mfma_f32_16x16x32_bf16(pa, pv1[tt], o[4 + tt], 0, 0, 0);
        ol = __builtin_amdgcn_mfma_f32_16x16x32_bf16(pa, ones, ol, 0, 0, 0);
    }

    // ---- block-level flash merge of 4 key-split partials ----
    if (dh == 0 && lr == 0) {
#pragma unroll
        for (int j = 0; j < 4; ++j) { Msh[kq][lk * 4 + j] = m[j]; Lsh[kq][lk * 4 + j] = ol[j]; }
    }
    __syncthreads();
    float fac[4];
#pragma unroll
    for (int j = 0; j < 4; ++j) {
        int q = lk * 4 + j;
        float M = fmaxf(fmaxf(Msh[0][q], Msh[1][q]), fmaxf(Msh[2][q], Msh[3][q]));
        fac[j] = __expf(m[j] - M);
    }
    if (tid < 16) {
        int q = tid;
        float M = fmaxf(fmaxf(Msh[0][q], Msh[1][q]), fmaxf(Msh[2][q], Msh[3][q]));
        float L = 0.f;
        for (int ww = 0; ww < 4; ++ww) L += __expf(Msh[ww][q] - M) * Lsh[ww][q];
        Lrow[q] = L;
    }
    for (int p = 0; p < 4; ++p) {
        if (kq == p) {   // both dh waves: disjoint column halves
#pragma unroll
            for (int t = 0; t < 8; ++t)
#pragma unroll
                for (int j = 0; j < 4; ++j)
                    Osum[lk * 4 + j][dbase + t * 16 + lr] += fac[j] * o[t][j];
        }
        __syncthreads();
    }
    // final: H = (ALPHA*Q + Osum/L) / (ALPHA+BETA); emit f32 and/or bf16+bf16^T
    for (int rep = 0; rep < 8; ++rep) {
        int e = rep * 512 + tid;
        int r = e >> 8;
        int cc = e & 255;
        float val = (ALPHA * Qo[(size_t)(q0 + r) * DD + cc] + Osum[r][cc] / Lrow[r])
                    * (1.0f / (ALPHA + BETA));
        Osum[r][cc] = val;
        if (Fout)  Fout[(size_t)(q0 + r) * DD + cc] = val;
        if (HvOut) HvOut[(size_t)(q0 + r) * DD + cc] = f2bf(val);
    }
    __syncthreads();
    if (HvtOut) {
#pragma unroll
        for (int p = 0; p < 8; ++p) {
            int cc = p * 32 + (tid >> 4);
            int r  = tid & 15;
            HvtOut[(size_t)cc * NN + q0 + r] = f2bf(Osum[r][cc]);
        }
    }
}

extern "C" void kernel_launch(void* const* d_in, const int* in_sizes, int n_in,
                              void* d_out, int out_size, void* d_ws, size_t ws_size,
                              hipStream_t stream) {
    const float* Q   = (const float*)d_in[0];
    const float* sim = (const float*)d_in[1];
    const float* W   = (const float*)d_in[2];
    const float* b   = (const float*)d_in[3];
    float* out = (float*)d_out;

    char* ws = (char*)d_ws;
    size_t off = 0;
    ushort* Hv   = (ushort*)(ws + off); off += (size_t)NN * DD * 2;
    ushort* HvtA = (ushort*)(ws + off); off += (size_t)NN * DD * 2;
    ushort* HvtB = (ushort*)(ws + off); off += (size_t)NN * DD * 2;
    ushort* Hp   = (ushort*)(ws + off); off += (size_t)NN * DD * 2;
    ushort* Wb   = (ushort*)(ws + off); off += (size_t)DD * DD * 2;
    unsigned* bits = (unsigned*)(ws + off); off += (size_t)NN * (NN / 32) * 4;

    k_wconv<<<DD * DD / 256, 256, 0, stream>>>(W, Wb);
    k_pack<<<NN, 256, 0, stream>>>(sim, bits);
    k_convert<<<(NN / 64) * (DD / 64), 256, 0, stream>>>(Q, Hv, HvtA);

    // iter 1: V = Q (HvtA); emit bf16 H (Hv) + transposed (HvtB)
    k_proj<<<NN / 64, 256, 0, stream>>>(Hv, Wb, b, Hp);
    k_attn<<<NN / 16, 512, 0, stream>>>(Hp, HvtA, bits, Q, Hv, HvtB, nullptr);

    // iter 2: V = H1 (HvtB); emit f32 out
    k_proj<<<NN / 64, 256, 0, stream>>>(Hv, Wb, b, Hp);
    k_attn<<<NN / 16, 512, 0, stream>>>(Hp, HvtB, bits, Q, nullptr, nullptr, out);
}

// Round 6
// 1042.536 us; speedup vs baseline: 1.5485x; 1.5485x over previous
//
#include <hip/hip_runtime.h>

#define NN 8192
#define DD 256
#define ALPHA 50.0f
#define BETA 1.0f
#define THR 8.0f

typedef __attribute__((ext_vector_type(8))) short short8;
typedef __attribute__((ext_vector_type(4))) float f32x4;

static __device__ __forceinline__ ushort f2bf(float f) {
    union { float f; unsigned u; } v; v.f = f;
    unsigned u = v.u;
    return (ushort)((u + 0x7fffu + ((u >> 16) & 1u)) >> 16);
}
static __device__ __forceinline__ float bf2f(ushort u) {
    union { unsigned u; float f; } v; v.u = ((unsigned)u) << 16;
    return v.f;
}

// --- W f32 -> bf16, once ---
__global__ void k_wconv(const float* __restrict__ W, ushort* __restrict__ Wb) {
    int i = blockIdx.x * 256 + threadIdx.x;
    Wb[i] = f2bf(W[i]);
}

// --- bitpack mask: bits[row][col/32], bit c = (sim[row][col] != 0) ---
__global__ __launch_bounds__(256) void k_pack(const float* __restrict__ sim,
                                              unsigned* __restrict__ bits) {
    int row = blockIdx.x;
    int w = threadIdx.x >> 6;
    int lane = threadIdx.x & 63;
    for (int p = 0; p < 32; ++p) {
        int col = p * 256 + w * 64 + lane;
        float v = sim[(size_t)row * NN + col];
        unsigned long long b = __ballot(v != 0.0f);
        if (lane == 0) {
            bits[row * (NN / 32) + p * 8 + w * 2]     = (unsigned)b;
            bits[row * (NN / 32) + p * 8 + w * 2 + 1] = (unsigned)(b >> 32);
        }
    }
}

// --- H f32 -> Hv bf16 (row-major) and Hvt bf16 (transposed [D][N]) ---
__global__ __launch_bounds__(256) void k_convert(const float* __restrict__ H,
                                                 ushort* __restrict__ Hv,
                                                 ushort* __restrict__ Hvt) {
    __shared__ ushort T[64][72];  // padded
    int tile = blockIdx.x;                  // 128 row-tiles * 4 col-tiles
    int r0 = (tile >> 2) * 64;
    int c0 = (tile & 3) * 64;
    int tid = threadIdx.x;
    int tr = tid >> 4;            // 0..15
    int tc = (tid & 15) * 4;      // 0..60
    for (int i = 0; i < 4; ++i) {
        int r = tr + i * 16;
        float4 v = *reinterpret_cast<const float4*>(H + (size_t)(r0 + r) * DD + c0 + tc);
        ushort4 o;
        o.x = f2bf(v.x); o.y = f2bf(v.y); o.z = f2bf(v.z); o.w = f2bf(v.w);
        *reinterpret_cast<ushort4*>(Hv + (size_t)(r0 + r) * DD + c0 + tc) = o;
        T[tc + 0][r] = o.x; T[tc + 1][r] = o.y; T[tc + 2][r] = o.z; T[tc + 3][r] = o.w;
    }
    __syncthreads();
    for (int i = 0; i < 4; ++i) {
        int c = tr + i * 16;      // local col -> global row of Hvt
        ushort4 o;
        o.x = T[c][tc + 0]; o.y = T[c][tc + 1]; o.z = T[c][tc + 2]; o.w = T[c][tc + 3];
        *reinterpret_cast<ushort4*>(Hvt + (size_t)(c0 + c) * NN + r0 + tc) = o;
    }
}

// --- Hp = bf16(Hv @ W^T + b) via MFMA; 256 blocks (64 rows x col-half) ---
__global__ __launch_bounds__(256) void k_proj(const ushort* __restrict__ Hv,
                                              const ushort* __restrict__ Wb,
                                              const float* __restrict__ b,
                                              ushort* __restrict__ Hp) {
    int w = threadIdx.x >> 6;
    int lane = threadIdx.x & 63;
    int row0 = (blockIdx.x >> 1) * 64 + w * 16;
    int ch = blockIdx.x & 1;
    int lr = lane & 15;
    int lk = lane >> 4;
    short8 af[8];
    for (int kk = 0; kk < 8; ++kk)
        af[kk] = *reinterpret_cast<const short8*>(Hv + (size_t)(row0 + lr) * DD + kk * 32 + lk * 8);
    for (int t = 0; t < 8; ++t) {
        f32x4 acc = {0.f, 0.f, 0.f, 0.f};
        int col = (ch * 8 + t) * 16 + lr;
        for (int kk = 0; kk < 8; ++kk) {
            short8 bf = *reinterpret_cast<const short8*>(Wb + (size_t)col * DD + kk * 32 + lk * 8);
            acc = __builtin_amdgcn_mfma_f32_16x16x32_bf16(af[kk], bf, acc, 0, 0, 0);
        }
        float bias = b[col];
        for (int j = 0; j < 4; ++j) {
            int row = row0 + lk * 4 + j;
            Hp[(size_t)row * DD + col] = f2bf(acc[j] + bias);
        }
    }
}

// --- fused masked flash attention, split-K partials ---
// grid = 512: decode xcd-aware: kq=(bid&7)>>1 (key quarter), qt=(bid>>3)*2|(bid&1).
// Block: 64 q-rows, 4 waves x 16 rows, ALL waves walk the same 2048-key quarter
// in lockstep (per-step barrier) -> K/V fragment loads L1-shared across waves.
// Outputs per (kq, row): Opart (bf16, unscaled e^{s-m} units), mpart, lpart.
__global__ __launch_bounds__(256) void k_attn(const ushort* __restrict__ Hp,
                                              const ushort* __restrict__ Hvt,
                                              const unsigned* __restrict__ bits,
                                              ushort* __restrict__ Opart,
                                              float* __restrict__ mpart,
                                              float* __restrict__ lpart) {
    __shared__ ushort Plds[4][16][36];  // per-wave private P tile

    const int tid = threadIdx.x;
    const int w = tid >> 6;
    const int lane = tid & 63;
    const int lr = lane & 15;
    const int lk = lane >> 4;
    const int bid = blockIdx.x;
    const int xcd = bid & 7;
    const int kq = xcd >> 1;
    const int qt = ((bid >> 3) << 1) | (xcd & 1);
    const int rw0 = qt * 64 + w * 16;   // this wave's 16 q-rows
    const int kstart = kq * (NN / 4);

    short8 qf[8];
#pragma unroll
    for (int kk = 0; kk < 8; ++kk)
        qf[kk] = *reinterpret_cast<const short8*>(Hp + (size_t)(rw0 + lr) * DD + kk * 32 + lk * 8);

    f32x4 o[17];
#pragma unroll
    for (int t = 0; t < 17; ++t) o[t] = {0.f, 0.f, 0.f, 0.f};
    float m[4] = {-1e30f, -1e30f, -1e30f, -1e30f};

    short8 ones;
#pragma unroll
    for (int e = 0; e < 8; ++e) ones[e] = (short)0x3f80;  // bf16 1.0

    const int rowbase = (rw0 + lk * 4) * (NN / 32);
    for (int step = 0; step < (NN / 4) / 32; ++step) {
        const int kb = kstart + step * 32;
        const int wi = kb >> 5;
        // mask words (broadcast)
        unsigned mwj[4];
#pragma unroll
        for (int j = 0; j < 4; ++j) mwj[j] = bits[rowbase + j * (NN / 32) + wi];
        // V prefetch, first half (in flight across QK^T + softmax)
        short8 pv0[8];
#pragma unroll
        for (int tt = 0; tt < 8; ++tt)
            pv0[tt] = *reinterpret_cast<const short8*>(Hvt + (size_t)(tt * 16 + lr) * NN + kb + lk * 8);

        f32x4 s0 = {0.f, 0.f, 0.f, 0.f}, s1 = {0.f, 0.f, 0.f, 0.f};
#pragma unroll
        for (int kk = 0; kk < 8; ++kk) {
            short8 k0 = *reinterpret_cast<const short8*>(Hp + (size_t)(kb + lr) * DD + kk * 32 + lk * 8);
            short8 k1 = *reinterpret_cast<const short8*>(Hp + (size_t)(kb + 16 + lr) * DD + kk * 32 + lk * 8);
            s0 = __builtin_amdgcn_mfma_f32_16x16x32_bf16(qf[kk], k0, s0, 0, 0, 0);
            s1 = __builtin_amdgcn_mfma_f32_16x16x32_bf16(qf[kk], k1, s1, 0, 0, 0);
        }
        // mask + defer-max check (no shuffles on light path)
        float c = -1e30f;
#pragma unroll
        for (int j = 0; j < 4; ++j) {
            float a0 = ((mwj[j] >> lr) & 1u) ? s0[j] : -1e30f;
            float a1 = ((mwj[j] >> (lr + 16)) & 1u) ? s1[j] : -1e30f;
            s0[j] = a0; s1[j] = a1;
            c = fmaxf(c, fmaxf(a0, a1) - m[j]);
        }
        if (__any(c > THR)) {   // rare: new-max rescale
#pragma unroll
            for (int j = 0; j < 4; ++j) {
                float mx = fmaxf(s0[j], s1[j]);
                mx = fmaxf(mx, __shfl_xor(mx, 1));
                mx = fmaxf(mx, __shfl_xor(mx, 2));
                mx = fmaxf(mx, __shfl_xor(mx, 4));
                mx = fmaxf(mx, __shfl_xor(mx, 8));
                float mn = fmaxf(m[j], mx);
                float scale = __expf(m[j] - mn);
                m[j] = mn;
#pragma unroll
                for (int t = 0; t < 17; ++t) o[t][j] *= scale;
            }
        }
        // P -> LDS (wave-private; masked entries underflow to 0; all-masked-so-far
        // junk exp(0)=1 wiped by scale=0 at the row's first real max)
#pragma unroll
        for (int j = 0; j < 4; ++j) {
            Plds[w][lk * 4 + j][lr]      = f2bf(__expf(s0[j] - m[j]));
            Plds[w][lk * 4 + j][16 + lr] = f2bf(__expf(s1[j] - m[j]));
        }
        // V prefetch, second half (issued before the LDS drain)
        short8 pv1[8];
#pragma unroll
        for (int tt = 0; tt < 8; ++tt)
            pv1[tt] = *reinterpret_cast<const short8*>(Hvt + (size_t)((8 + tt) * 16 + lr) * NN + kb + lk * 8);
        asm volatile("s_waitcnt lgkmcnt(0)" ::: "memory");
        __builtin_amdgcn_sched_barrier(0);
        short8 pa = *reinterpret_cast<const short8*>(&Plds[w][lr][lk * 8]);
        // O += P @ V ; l-sum via ones column
#pragma unroll
        for (int tt = 0; tt < 8; ++tt)
            o[tt] = __builtin_amdgcn_mfma_f32_16x16x32_bf16(pa, pv0[tt], o[tt], 0, 0, 0);
#pragma unroll
        for (int tt = 0; tt < 8; ++tt)
            o[8 + tt] = __builtin_amdgcn_mfma_f32_16x16x32_bf16(pa, pv1[tt], o[8 + tt], 0, 0, 0);
        o[16] = __builtin_amdgcn_mfma_f32_16x16x32_bf16(pa, ones, o[16], 0, 0, 0);
        __syncthreads();   // lockstep waves -> L1 reuse of K/V tiles
    }

    // ---- write split-K partials (unscaled; merge kernel applies exp(m-M)) ----
    ushort* op = Opart + ((size_t)kq * NN + rw0) * DD;
#pragma unroll
    for (int t = 0; t < 16; ++t)
#pragma unroll
        for (int j = 0; j < 4; ++j)
            op[(size_t)(lk * 4 + j) * DD + t * 16 + lr] = f2bf(o[t][j]);
    if (lr == 0) {
#pragma unroll
        for (int j = 0; j < 4; ++j) {
            mpart[kq * NN + rw0 + lk * 4 + j] = m[j];
            lpart[kq * NN + rw0 + lk * 4 + j] = o[16][j];
        }
    }
}

// --- merge 4 split-K partials + CRF epilogue: dst = (ALPHA*Q + O/L)/(ALPHA+BETA) ---
// grid = 256 blocks x 32 rows; wave w: rows r0+w*8, lane covers 4 cols (float4)
__global__ __launch_bounds__(256) void k_merge(const ushort* __restrict__ Opart,
                                               const float* __restrict__ mpart,
                                               const float* __restrict__ lpart,
                                               const float* __restrict__ Qo,
                                               float* __restrict__ dst) {
    int w = threadIdx.x >> 6;
    int lane = threadIdx.x & 63;
    int r0 = blockIdx.x * 32 + w * 8;
    for (int rr = 0; rr < 8; ++rr) {
        int r = r0 + rr;
        float m0 = mpart[0 * NN + r], m1 = mpart[1 * NN + r];
        float m2 = mpart[2 * NN + r], m3 = mpart[3 * NN + r];
        float M = fmaxf(fmaxf(m0, m1), fmaxf(m2, m3));
        float f0 = __expf(m0 - M), f1 = __expf(m1 - M);
        float f2 = __expf(m2 - M), f3 = __expf(m3 - M);
        float L = f0 * lpart[0 * NN + r] + f1 * lpart[1 * NN + r] +
                  f2 * lpart[2 * NN + r] + f3 * lpart[3 * NN + r];
        float invL = 1.0f / L;
        int c = lane * 4;
        ushort4 u0 = *reinterpret_cast<const ushort4*>(Opart + ((size_t)0 * NN + r) * DD + c);
        ushort4 u1 = *reinterpret_cast<const ushort4*>(Opart + ((size_t)1 * NN + r) * DD + c);
        ushort4 u2 = *reinterpret_cast<const ushort4*>(Opart + ((size_t)2 * NN + r) * DD + c);
        ushort4 u3 = *reinterpret_cast<const ushort4*>(Opart + ((size_t)3 * NN + r) * DD + c);
        float4 qv = *reinterpret_cast<const float4*>(Qo + (size_t)r * DD + c);
        float4 out;
        out.x = (ALPHA * qv.x + (f0 * bf2f(u0.x) + f1 * bf2f(u1.x) + f2 * bf2f(u2.x) + f3 * bf2f(u3.x)) * invL) * (1.0f / (ALPHA + BETA));
        out.y = (ALPHA * qv.y + (f0 * bf2f(u0.y) + f1 * bf2f(u1.y) + f2 * bf2f(u2.y) + f3 * bf2f(u3.y)) * invL) * (1.0f / (ALPHA + BETA));
        out.z = (ALPHA * qv.z + (f0 * bf2f(u0.z) + f1 * bf2f(u1.z) + f2 * bf2f(u2.z) + f3 * bf2f(u3.z)) * invL) * (1.0f / (ALPHA + BETA));
        out.w = (ALPHA * qv.w + (f0 * bf2f(u0.w) + f1 * bf2f(u1.w) + f2 * bf2f(u2.w) + f3 * bf2f(u3.w)) * invL) * (1.0f / (ALPHA + BETA));
        *reinterpret_cast<float4*>(dst + (size_t)r * DD + c) = out;
    }
}

extern "C" void kernel_launch(void* const* d_in, const int* in_sizes, int n_in,
                              void* d_out, int out_size, void* d_ws, size_t ws_size,
                              hipStream_t stream) {
    const float* Q   = (const float*)d_in[0];
    const float* sim = (const float*)d_in[1];
    const float* W   = (const float*)d_in[2];
    const float* b   = (const float*)d_in[3];
    float* out = (float*)d_out;

    char* ws = (char*)d_ws;
    size_t off = 0;
    ushort* Hv   = (ushort*)(ws + off); off += (size_t)NN * DD * 2;
    ushort* HvtA = (ushort*)(ws + off); off += (size_t)NN * DD * 2;
    ushort* HvtB = (ushort*)(ws + off); off += (size_t)NN * DD * 2;
    ushort* Hp   = (ushort*)(ws + off); off += (size_t)NN * DD * 2;
    ushort* Wb   = (ushort*)(ws + off); off += (size_t)DD * DD * 2;
    unsigned* bits = (unsigned*)(ws + off); off += (size_t)NN * (NN / 32) * 4;
    float*  H1   = (float*)(ws + off);  off += (size_t)NN * DD * 4;
    ushort* Opart = (ushort*)(ws + off); off += (size_t)4 * NN * DD * 2;
    float*  mpart = (float*)(ws + off);  off += (size_t)4 * NN * 4;
    float*  lpart = (float*)(ws + off);  off += (size_t)4 * NN * 4;

    k_wconv<<<DD * DD / 256, 256, 0, stream>>>(W, Wb);
    k_pack<<<NN, 256, 0, stream>>>(sim, bits);
    k_convert<<<(NN / 64) * (DD / 64), 256, 0, stream>>>(Q, Hv, HvtA);

    // iter 1: V = Q (HvtA)
    k_proj<<<NN / 32, 256, 0, stream>>>(Hv, Wb, b, Hp);
    k_attn<<<NN / 16, 256, 0, stream>>>(Hp, HvtA, bits, Opart, mpart, lpart);
    k_merge<<<NN / 32, 256, 0, stream>>>(Opart, mpart, lpart, Q, H1);
    k_convert<<<(NN / 64) * (DD / 64), 256, 0, stream>>>(H1, Hv, HvtB);

    // iter 2: V = H1 (HvtB)
    k_proj<<<NN / 32, 256, 0, stream>>>(Hv, Wb, b, Hp);
    k_attn<<<NN / 16, 256, 0, stream>>>(Hp, HvtB, bits, Opart, mpart, lpart);
    k_merge<<<NN / 32, 256, 0, stream>>>(Opart, mpart, lpart, Q, out);
}

// Round 7
// 410.498 us; speedup vs baseline: 3.9328x; 2.5397x over previous
//
#include <hip/hip_runtime.h>

#define NN 8192
#define DD 256
#define ALPHA 50.0f
#define BETA 1.0f
#define THR 8.0f
#define KQ 8                 // key splits
#define KEYS (NN / KQ)       // 1024 keys per block
#define STEPS (KEYS / 32)    // 32

typedef __attribute__((ext_vector_type(8))) short short8;
typedef __attribute__((ext_vector_type(4))) float f32x4;

static __device__ __forceinline__ ushort f2bf(float f) {
    union { float f; unsigned u; } v; v.f = f;
    unsigned u = v.u;
    return (ushort)((u + 0x7fffu + ((u >> 16) & 1u)) >> 16);
}
static __device__ __forceinline__ float bf2f(ushort u) {
    union { unsigned u; float f; } v; v.u = ((unsigned)u) << 16;
    return v.f;
}
static __device__ __forceinline__ void gl_lds16(const ushort* g, ushort* l) {
    __builtin_amdgcn_global_load_lds(
        (const __attribute__((address_space(1))) unsigned int*)g,
        (__attribute__((address_space(3))) unsigned int*)l, 16, 0, 0);
}

// --- W f32 -> bf16, once ---
__global__ void k_wconv(const float* __restrict__ W, ushort* __restrict__ Wb) {
    int i = blockIdx.x * 256 + threadIdx.x;
    Wb[i] = f2bf(W[i]);
}

// --- bitpack mask: bits[row][col/32] ---
__global__ __launch_bounds__(256) void k_pack(const float* __restrict__ sim,
                                              unsigned* __restrict__ bits) {
    int row = blockIdx.x;
    int w = threadIdx.x >> 6;
    int lane = threadIdx.x & 63;
    for (int p = 0; p < 32; ++p) {
        int col = p * 256 + w * 64 + lane;
        float v = sim[(size_t)row * NN + col];
        unsigned long long b = __ballot(v != 0.0f);
        if (lane == 0) {
            bits[row * (NN / 32) + p * 8 + w * 2]     = (unsigned)b;
            bits[row * (NN / 32) + p * 8 + w * 2 + 1] = (unsigned)(b >> 32);
        }
    }
}

// --- H f32 -> Hv bf16 (row-major) and Hvt bf16 (transposed [D][N]) ---
__global__ __launch_bounds__(256) void k_convert(const float* __restrict__ H,
                                                 ushort* __restrict__ Hv,
                                                 ushort* __restrict__ Hvt) {
    __shared__ ushort T[64][72];
    int tile = blockIdx.x;
    int r0 = (tile >> 2) * 64;
    int c0 = (tile & 3) * 64;
    int tid = threadIdx.x;
    int tr = tid >> 4;
    int tc = (tid & 15) * 4;
    for (int i = 0; i < 4; ++i) {
        int r = tr + i * 16;
        float4 v = *reinterpret_cast<const float4*>(H + (size_t)(r0 + r) * DD + c0 + tc);
        ushort4 o;
        o.x = f2bf(v.x); o.y = f2bf(v.y); o.z = f2bf(v.z); o.w = f2bf(v.w);
        *reinterpret_cast<ushort4*>(Hv + (size_t)(r0 + r) * DD + c0 + tc) = o;
        T[tc + 0][r] = o.x; T[tc + 1][r] = o.y; T[tc + 2][r] = o.z; T[tc + 3][r] = o.w;
    }
    __syncthreads();
    for (int i = 0; i < 4; ++i) {
        int c = tr + i * 16;
        ushort4 o;
        o.x = T[c][tc + 0]; o.y = T[c][tc + 1]; o.z = T[c][tc + 2]; o.w = T[c][tc + 3];
        *reinterpret_cast<ushort4*>(Hvt + (size_t)(c0 + c) * NN + r0 + tc) = o;
    }
}

// --- Hp = bf16(Hv @ W^T + b) ---
__global__ __launch_bounds__(256) void k_proj(const ushort* __restrict__ Hv,
                                              const ushort* __restrict__ Wb,
                                              const float* __restrict__ b,
                                              ushort* __restrict__ Hp) {
    int w = threadIdx.x >> 6;
    int lane = threadIdx.x & 63;
    int row0 = (blockIdx.x >> 1) * 64 + w * 16;
    int ch = blockIdx.x & 1;
    int lr = lane & 15;
    int lk = lane >> 4;
    short8 af[8];
    for (int kk = 0; kk < 8; ++kk)
        af[kk] = *reinterpret_cast<const short8*>(Hv + (size_t)(row0 + lr) * DD + kk * 32 + lk * 8);
    for (int t = 0; t < 8; ++t) {
        f32x4 acc = {0.f, 0.f, 0.f, 0.f};
        int col = (ch * 8 + t) * 16 + lr;
        for (int kk = 0; kk < 8; ++kk) {
            short8 bf = *reinterpret_cast<const short8*>(Wb + (size_t)col * DD + kk * 32 + lk * 8);
            acc = __builtin_amdgcn_mfma_f32_16x16x32_bf16(af[kk], bf, acc, 0, 0, 0);
        }
        float bias = b[col];
        for (int j = 0; j < 4; ++j) {
            int row = row0 + lk * 4 + j;
            Hp[(size_t)row * DD + col] = f2bf(acc[j] + bias);
        }
    }
}

// --- fused masked flash attention, split-K partials, LDS-staged K/V ---
// grid = 1024: kq = bid&7 (XCD-local 1024-key range), qt = bid>>3 (64 q-rows).
// 4 waves x 16 q-rows. K tile [32][256] and V tile [256][32] double-buffered in
// LDS via global_load_lds (issued one step ahead); XOR-swizzled chunks (G4/T2).
#define SMEM_ATTN (2 * 32 * 256 * 2 + 2 * 256 * 32 * 2 + 4 * 16 * 36 * 2)
__global__ __launch_bounds__(256) void k_attn(const ushort* __restrict__ Hp,
                                              const ushort* __restrict__ Hvt,
                                              const unsigned* __restrict__ bits,
                                              ushort* __restrict__ Opart,
                                              float* __restrict__ mpart,
                                              float* __restrict__ lpart) {
    extern __shared__ char smem[];
    ushort* KlB = (ushort*)smem;                  // 2 x [32][256] swizzled
    ushort* VlB = (ushort*)(smem + 32768);        // 2 x [256][32] swizzled
    ushort* Pl  = (ushort*)(smem + 65536);        // 4 x [16][36]

    const int tid = threadIdx.x;
    const int w = tid >> 6;
    const int lane = tid & 63;
    const int lr = lane & 15;
    const int lk = lane >> 4;
    const int bid = blockIdx.x;
    const int kq = bid & 7;
    const int qt = bid >> 3;
    const int rw0 = qt * 64 + w * 16;
    const int kstart = kq * KEYS;

    // staging: 1024 16B-slots per tile, wave w covers slots [w*256, +256) in 4 insts
    auto stageK = [&](int buf, int kb) {
        const ushort* Kg = Hp + (size_t)kb * DD;      // contiguous 16KB
        ushort* base = KlB + buf * (32 * 256);
#pragma unroll
        for (int i = 0; i < 4; ++i) {
            int S = (w * 4 + i) * 64 + lane;
            int r = S >> 5, cp = S & 31;
            int cc = cp ^ (r & 7);
            gl_lds16(Kg + r * 256 + cc * 8, base + (w * 4 + i) * 512);
        }
    };
    auto stageV = [&](int buf, int kb) {
        ushort* base = VlB + buf * (256 * 32);
#pragma unroll
        for (int i = 0; i < 4; ++i) {
            int S = (w * 4 + i) * 64 + lane;
            int r = S >> 2, cp = S & 3;
            int cc = cp ^ (r & 3);
            gl_lds16(Hvt + (size_t)r * NN + kb + cc * 8, base + (w * 4 + i) * 512);
        }
    };

    short8 qf[8];
#pragma unroll
    for (int kk = 0; kk < 8; ++kk)
        qf[kk] = *reinterpret_cast<const short8*>(Hp + (size_t)(rw0 + lr) * DD + kk * 32 + lk * 8);

    f32x4 o[17];
#pragma unroll
    for (int t = 0; t < 17; ++t) o[t] = {0.f, 0.f, 0.f, 0.f};
    float m[4] = {-1e30f, -1e30f, -1e30f, -1e30f};

    short8 ones;
#pragma unroll
    for (int e = 0; e < 8; ++e) ones[e] = (short)0x3f80;  // bf16 1.0

    stageK(0, kstart);
    stageV(0, kstart);
    __syncthreads();

    const int rowbase = (rw0 + lk * 4) * (NN / 32);
    int cur = 0;
    for (int step = 0; step < STEPS; ++step) {
        const int kb = kstart + step * 32;
        // prefetch next tile into other buffer (drained at this step's barrier)
        if (step + 1 < STEPS) {
            stageK(cur ^ 1, kb + 32);
            stageV(cur ^ 1, kb + 32);
        }
        // mask words (broadcast)
        const int wi = kb >> 5;
        unsigned mwj[4];
#pragma unroll
        for (int j = 0; j < 4; ++j) mwj[j] = bits[rowbase + j * (NN / 32) + wi];

        // QK^T from LDS K tile (swizzled ds_read_b128)
        const char* Kb = (const char*)(KlB + cur * (32 * 256));
        f32x4 s0 = {0.f, 0.f, 0.f, 0.f}, s1 = {0.f, 0.f, 0.f, 0.f};
#pragma unroll
        for (int kk = 0; kk < 8; ++kk) {
            int cp = (kk * 4 + lk) ^ (lr & 7);
            short8 k0 = *reinterpret_cast<const short8*>(Kb + (lr << 9) + (cp << 4));
            short8 k1 = *reinterpret_cast<const short8*>(Kb + ((16 + lr) << 9) + (cp << 4));
            s0 = __builtin_amdgcn_mfma_f32_16x16x32_bf16(qf[kk], k0, s0, 0, 0, 0);
            s1 = __builtin_amdgcn_mfma_f32_16x16x32_bf16(qf[kk], k1, s1, 0, 0, 0);
        }
        // mask + defer-max
        float c = -1e30f;
#pragma unroll
        for (int j = 0; j < 4; ++j) {
            float a0 = ((mwj[j] >> lr) & 1u) ? s0[j] : -1e30f;
            float a1 = ((mwj[j] >> (lr + 16)) & 1u) ? s1[j] : -1e30f;
            s0[j] = a0; s1[j] = a1;
            c = fmaxf(c, fmaxf(a0, a1) - m[j]);
        }
        if (__any(c > THR)) {
#pragma unroll
            for (int j = 0; j < 4; ++j) {
                float mx = fmaxf(s0[j], s1[j]);
                mx = fmaxf(mx, __shfl_xor(mx, 1));
                mx = fmaxf(mx, __shfl_xor(mx, 2));
                mx = fmaxf(mx, __shfl_xor(mx, 4));
                mx = fmaxf(mx, __shfl_xor(mx, 8));
                float mn = fmaxf(m[j], mx);
                float scale = __expf(m[j] - mn);
                m[j] = mn;
#pragma unroll
                for (int t = 0; t < 17; ++t) o[t][j] *= scale;
            }
        }
        // P -> LDS (wave-private; masked entries underflow to 0; pre-first-max
        // junk exp(0)=1 wiped by scale=0 at the row's first real max)
        ushort* Pw = Pl + (size_t)w * 16 * 36;
#pragma unroll
        for (int j = 0; j < 4; ++j) {
            Pw[(lk * 4 + j) * 36 + lr]      = f2bf(__expf(s0[j] - m[j]));
            Pw[(lk * 4 + j) * 36 + 16 + lr] = f2bf(__expf(s1[j] - m[j]));
        }
        asm volatile("s_waitcnt lgkmcnt(0)" ::: "memory");
        __builtin_amdgcn_sched_barrier(0);
        short8 pa = *reinterpret_cast<const short8*>(Pw + lr * 36 + lk * 8);
        // O += P @ V from LDS V tile
        const char* Vb = (const char*)(VlB + cur * (256 * 32));
        int vcp = lk ^ (lr & 3);
#pragma unroll
        for (int t = 0; t < 16; ++t) {
            short8 vf = *reinterpret_cast<const short8*>(Vb + ((t * 16 + lr) << 6) + (vcp << 4));
            o[t] = __builtin_amdgcn_mfma_f32_16x16x32_bf16(pa, vf, o[t], 0, 0, 0);
        }
        o[16] = __builtin_amdgcn_mfma_f32_16x16x32_bf16(pa, ones, o[16], 0, 0, 0);
        __syncthreads();   // drains vmcnt (staged tile ready) + LDS reads done
        cur ^= 1;
    }

    // ---- write split-K partials ----
    ushort* op = Opart + ((size_t)kq * NN + rw0) * DD;
#pragma unroll
    for (int t = 0; t < 16; ++t)
#pragma unroll
        for (int j = 0; j < 4; ++j)
            op[(size_t)(lk * 4 + j) * DD + t * 16 + lr] = f2bf(o[t][j]);
    if (lr == 0) {
#pragma unroll
        for (int j = 0; j < 4; ++j) {
            mpart[kq * NN + rw0 + lk * 4 + j] = m[j];
            lpart[kq * NN + rw0 + lk * 4 + j] = o[16][j];
        }
    }
}

// --- merge 8 split-K partials + CRF epilogue ---
__global__ __launch_bounds__(256) void k_merge8(const ushort* __restrict__ Opart,
                                                const float* __restrict__ mpart,
                                                const float* __restrict__ lpart,
                                                const float* __restrict__ Qo,
                                                float* __restrict__ dst) {
    int w = threadIdx.x >> 6;
    int lane = threadIdx.x & 63;
    int r0 = blockIdx.x * 32 + w * 8;
    for (int rr = 0; rr < 8; ++rr) {
        int r = r0 + rr;
        float mv[8], f[8];
        float M = -1e30f;
#pragma unroll
        for (int p = 0; p < 8; ++p) { mv[p] = mpart[p * NN + r]; M = fmaxf(M, mv[p]); }
        float L = 0.f;
#pragma unroll
        for (int p = 0; p < 8; ++p) { f[p] = __expf(mv[p] - M); L += f[p] * lpart[p * NN + r]; }
        float invL = 1.0f / L;
        int c = lane * 4;
        float a0 = 0.f, a1 = 0.f, a2 = 0.f, a3 = 0.f;
#pragma unroll
        for (int p = 0; p < 8; ++p) {
            ushort4 u = *reinterpret_cast<const ushort4*>(Opart + ((size_t)p * NN + r) * DD + c);
            a0 += f[p] * bf2f(u.x); a1 += f[p] * bf2f(u.y);
            a2 += f[p] * bf2f(u.z); a3 += f[p] * bf2f(u.w);
        }
        float4 qv = *reinterpret_cast<const float4*>(Qo + (size_t)r * DD + c);
        float4 ov;
        ov.x = (ALPHA * qv.x + a0 * invL) * (1.0f / (ALPHA + BETA));
        ov.y = (ALPHA * qv.y + a1 * invL) * (1.0f / (ALPHA + BETA));
        ov.z = (ALPHA * qv.z + a2 * invL) * (1.0f / (ALPHA + BETA));
        ov.w = (ALPHA * qv.w + a3 * invL) * (1.0f / (ALPHA + BETA));
        *reinterpret_cast<float4*>(dst + (size_t)r * DD + c) = ov;
    }
}

extern "C" void kernel_launch(void* const* d_in, const int* in_sizes, int n_in,
                              void* d_out, int out_size, void* d_ws, size_t ws_size,
                              hipStream_t stream) {
    const float* Q   = (const float*)d_in[0];
    const float* sim = (const float*)d_in[1];
    const float* W   = (const float*)d_in[2];
    const float* b   = (const float*)d_in[3];
    float* out = (float*)d_out;

    char* ws = (char*)d_ws;
    size_t off = 0;
    ushort* Hv   = (ushort*)(ws + off); off += (size_t)NN * DD * 2;
    ushort* HvtA = (ushort*)(ws + off); off += (size_t)NN * DD * 2;
    ushort* HvtB = (ushort*)(ws + off); off += (size_t)NN * DD * 2;
    ushort* Hp   = (ushort*)(ws + off); off += (size_t)NN * DD * 2;
    ushort* Wb   = (ushort*)(ws + off); off += (size_t)DD * DD * 2;
    unsigned* bits = (unsigned*)(ws + off); off += (size_t)NN * (NN / 32) * 4;
    float*  H1   = (float*)(ws + off);  off += (size_t)NN * DD * 4;
    ushort* Opart = (ushort*)(ws + off); off += (size_t)KQ * NN * DD * 2;
    float*  mpart = (float*)(ws + off);  off += (size_t)KQ * NN * 4;
    float*  lpart = (float*)(ws + off);  off += (size_t)KQ * NN * 4;

    (void)hipFuncSetAttribute((const void*)k_attn,
                              hipFuncAttributeMaxDynamicSharedMemorySize, SMEM_ATTN);

    k_wconv<<<DD * DD / 256, 256, 0, stream>>>(W, Wb);
    k_pack<<<NN, 256, 0, stream>>>(sim, bits);
    k_convert<<<(NN / 64) * (DD / 64), 256, 0, stream>>>(Q, Hv, HvtA);

    // iter 1: V = Q (HvtA)
    k_proj<<<NN / 32, 256, 0, stream>>>(Hv, Wb, b, Hp);
    k_attn<<<(NN / 64) * KQ, 256, SMEM_ATTN, stream>>>(Hp, HvtA, bits, Opart, mpart, lpart);
    k_merge8<<<NN / 32, 256, 0, stream>>>(Opart, mpart, lpart, Q, H1);
    k_convert<<<(NN / 64) * (DD / 64), 256, 0, stream>>>(H1, Hv, HvtB);

    // iter 2: V = H1 (HvtB)
    k_proj<<<NN / 32, 256, 0, stream>>>(Hv, Wb, b, Hp);
    k_attn<<<(NN / 64) * KQ, 256, SMEM_ATTN, stream>>>(Hp, HvtB, bits, Opart, mpart, lpart);
    k_merge8<<<NN / 32, 256, 0, stream>>>(Opart, mpart, lpart, Q, out);
}

// Round 8
// 380.327 us; speedup vs baseline: 4.2447x; 1.0793x over previous
//
#include <hip/hip_runtime.h>

#define NN 8192
#define DD 256
#define ALPHA 50.0f
#define BETA 1.0f
#define THR 8.0f
#define KQ 8                 // key splits
#define KEYS (NN / KQ)       // 1024 keys per block
#define STEPS (KEYS / 32)    // 32

typedef __attribute__((ext_vector_type(8))) short short8;
typedef __attribute__((ext_vector_type(4))) float f32x4;

static __device__ __forceinline__ ushort f2bf(float f) {
    union { float f; unsigned u; } v; v.f = f;
    unsigned u = v.u;
    return (ushort)((u + 0x7fffu + ((u >> 16) & 1u)) >> 16);
}
static __device__ __forceinline__ float bf2f(ushort u) {
    union { unsigned u; float f; } v; v.u = ((unsigned)u) << 16;
    return v.f;
}
static __device__ __forceinline__ void gl_lds16(const ushort* g, ushort* l) {
    __builtin_amdgcn_global_load_lds(
        (const __attribute__((address_space(1))) unsigned int*)g,
        (__attribute__((address_space(3))) unsigned int*)l, 16, 0, 0);
}

// --- W f32 -> bf16, once ---
__global__ void k_wconv(const float* __restrict__ W, ushort* __restrict__ Wb) {
    int i = blockIdx.x * 256 + threadIdx.x;
    Wb[i] = f2bf(W[i]);
}

// --- bitpack mask: bits[row][col/32]; float4 loads + LDS nibble assembly ---
__global__ __launch_bounds__(256) void k_pack(const float* __restrict__ sim,
                                              unsigned* __restrict__ bits) {
    __shared__ unsigned char nibs[256];
    int row = blockIdx.x;
    int tid = threadIdx.x;
    for (int p = 0; p < 8; ++p) {
        int col = p * 1024 + tid * 4;
        float4 v = *reinterpret_cast<const float4*>(sim + (size_t)row * NN + col);
        unsigned char nib = (unsigned char)((v.x != 0.f) | ((v.y != 0.f) << 1) |
                                            ((v.z != 0.f) << 2) | ((v.w != 0.f) << 3));
        nibs[tid] = nib;
        __syncthreads();
        if (tid < 32) {
            unsigned word = 0;
#pragma unroll
            for (int i = 0; i < 8; ++i) word |= ((unsigned)nibs[tid * 8 + i]) << (4 * i);
            bits[row * (NN / 32) + p * 32 + tid] = word;
        }
        __syncthreads();
    }
}

// --- H f32 -> Hv bf16 (row-major) and Hvt bf16 (transposed [D][N]) ---
__global__ __launch_bounds__(256) void k_convert(const float* __restrict__ H,
                                                 ushort* __restrict__ Hv,
                                                 ushort* __restrict__ Hvt) {
    __shared__ ushort T[64][72];
    int tile = blockIdx.x;
    int r0 = (tile >> 2) * 64;
    int c0 = (tile & 3) * 64;
    int tid = threadIdx.x;
    int tr = tid >> 4;
    int tc = (tid & 15) * 4;
    for (int i = 0; i < 4; ++i) {
        int r = tr + i * 16;
        float4 v = *reinterpret_cast<const float4*>(H + (size_t)(r0 + r) * DD + c0 + tc);
        ushort4 o;
        o.x = f2bf(v.x); o.y = f2bf(v.y); o.z = f2bf(v.z); o.w = f2bf(v.w);
        *reinterpret_cast<ushort4*>(Hv + (size_t)(r0 + r) * DD + c0 + tc) = o;
        T[tc + 0][r] = o.x; T[tc + 1][r] = o.y; T[tc + 2][r] = o.z; T[tc + 3][r] = o.w;
    }
    __syncthreads();
    for (int i = 0; i < 4; ++i) {
        int c = tr + i * 16;
        ushort4 o;
        o.x = T[c][tc + 0]; o.y = T[c][tc + 1]; o.z = T[c][tc + 2]; o.w = T[c][tc + 3];
        *reinterpret_cast<ushort4*>(Hvt + (size_t)(c0 + c) * NN + r0 + tc) = o;
    }
}

// --- Hp = bf16(Hv @ W^T + b) ---
__global__ __launch_bounds__(256) void k_proj(const ushort* __restrict__ Hv,
                                              const ushort* __restrict__ Wb,
                                              const float* __restrict__ b,
                                              ushort* __restrict__ Hp) {
    int w = threadIdx.x >> 6;
    int lane = threadIdx.x & 63;
    int row0 = (blockIdx.x >> 1) * 64 + w * 16;
    int ch = blockIdx.x & 1;
    int lr = lane & 15;
    int lk = lane >> 4;
    short8 af[8];
    for (int kk = 0; kk < 8; ++kk)
        af[kk] = *reinterpret_cast<const short8*>(Hv + (size_t)(row0 + lr) * DD + kk * 32 + lk * 8);
    for (int t = 0; t < 8; ++t) {
        f32x4 acc = {0.f, 0.f, 0.f, 0.f};
        int col = (ch * 8 + t) * 16 + lr;
        for (int kk = 0; kk < 8; ++kk) {
            short8 bf = *reinterpret_cast<const short8*>(Wb + (size_t)col * DD + kk * 32 + lk * 8);
            acc = __builtin_amdgcn_mfma_f32_16x16x32_bf16(af[kk], bf, acc, 0, 0, 0);
        }
        float bias = b[col];
        for (int j = 0; j < 4; ++j) {
            int row = row0 + lk * 4 + j;
            Hp[(size_t)row * DD + col] = f2bf(acc[j] + bias);
        }
    }
}

// --- fused masked flash attention, split-K partials, LDS-staged K/V ---
// grid = 1024: kq = bid&7 (XCD-local 1024-key range), qt = bid>>3 (64 q-rows).
// K tile [32][256] swizzle cc = cp ^ (r&7); V tile [256][32] swizzle
// cc = cp ^ ((r>>2)&3)  [fixed: r&3 gave 4-way conflicts on PV reads].
#define SMEM_ATTN (2 * 32 * 256 * 2 + 2 * 256 * 32 * 2 + 4 * 16 * 36 * 2)
__global__ __launch_bounds__(256) void k_attn(const ushort* __restrict__ Hp,
                                              const ushort* __restrict__ Hvt,
                                              const unsigned* __restrict__ bits,
                                              ushort* __restrict__ Opart,
                                              float* __restrict__ mpart,
                                              float* __restrict__ lpart) {
    extern __shared__ char smem[];
    ushort* KlB = (ushort*)smem;                  // 2 x [32][256] swizzled
    ushort* VlB = (ushort*)(smem + 32768);        // 2 x [256][32] swizzled
    ushort* Pl  = (ushort*)(smem + 65536);        // 4 x [16][36]

    const int tid = threadIdx.x;
    const int w = tid >> 6;
    const int lane = tid & 63;
    const int lr = lane & 15;
    const int lk = lane >> 4;
    const int bid = blockIdx.x;
    const int kq = bid & 7;
    const int qt = bid >> 3;
    const int rw0 = qt * 64 + w * 16;
    const int kstart = kq * KEYS;

    auto stageK = [&](int buf, int kb) {
        const ushort* Kg = Hp + (size_t)kb * DD;
        ushort* base = KlB + buf * (32 * 256);
#pragma unroll
        for (int i = 0; i < 4; ++i) {
            int S = (w * 4 + i) * 64 + lane;
            int r = S >> 5, cp = S & 31;
            int cc = cp ^ (r & 7);
            gl_lds16(Kg + r * 256 + cc * 8, base + (w * 4 + i) * 512);
        }
    };
    auto stageV = [&](int buf, int kb) {
        ushort* base = VlB + buf * (256 * 32);
#pragma unroll
        for (int i = 0; i < 4; ++i) {
            int S = (w * 4 + i) * 64 + lane;
            int r = S >> 2, cp = S & 3;
            int cc = cp ^ ((r >> 2) & 3);
            gl_lds16(Hvt + (size_t)r * NN + kb + cc * 8, base + (w * 4 + i) * 512);
        }
    };

    short8 qf[8];
#pragma unroll
    for (int kk = 0; kk < 8; ++kk)
        qf[kk] = *reinterpret_cast<const short8*>(Hp + (size_t)(rw0 + lr) * DD + kk * 32 + lk * 8);

    f32x4 o[17];
#pragma unroll
    for (int t = 0; t < 17; ++t) o[t] = {0.f, 0.f, 0.f, 0.f};
    float m[4] = {-1e30f, -1e30f, -1e30f, -1e30f};

    short8 ones;
#pragma unroll
    for (int e = 0; e < 8; ++e) ones[e] = (short)0x3f80;  // bf16 1.0

    stageK(0, kstart);
    stageV(0, kstart);
    __syncthreads();

    const int rowbase = (rw0 + lk * 4) * (NN / 32);
    int cur = 0;
    for (int step = 0; step < STEPS; ++step) {
        const int kb = kstart + step * 32;
        if (step + 1 < STEPS) {
            stageK(cur ^ 1, kb + 32);
            stageV(cur ^ 1, kb + 32);
        }
        const int wi = kb >> 5;
        unsigned mwj[4];
#pragma unroll
        for (int j = 0; j < 4; ++j) mwj[j] = bits[rowbase + j * (NN / 32) + wi];

        // QK^T from LDS K tile (swizzled ds_read_b128)
        const char* Kb = (const char*)(KlB + cur * (32 * 256));
        f32x4 s0 = {0.f, 0.f, 0.f, 0.f}, s1 = {0.f, 0.f, 0.f, 0.f};
#pragma unroll
        for (int kk = 0; kk < 8; ++kk) {
            int cp = (kk * 4 + lk) ^ (lr & 7);
            short8 k0 = *reinterpret_cast<const short8*>(Kb + (lr << 9) + (cp << 4));
            short8 k1 = *reinterpret_cast<const short8*>(Kb + ((16 + lr) << 9) + (cp << 4));
            s0 = __builtin_amdgcn_mfma_f32_16x16x32_bf16(qf[kk], k0, s0, 0, 0, 0);
            s1 = __builtin_amdgcn_mfma_f32_16x16x32_bf16(qf[kk], k1, s1, 0, 0, 0);
        }
        // mask + defer-max
        float c = -1e30f;
#pragma unroll
        for (int j = 0; j < 4; ++j) {
            float a0 = ((mwj[j] >> lr) & 1u) ? s0[j] : -1e30f;
            float a1 = ((mwj[j] >> (lr + 16)) & 1u) ? s1[j] : -1e30f;
            s0[j] = a0; s1[j] = a1;
            c = fmaxf(c, fmaxf(a0, a1) - m[j]);
        }
        if (__any(c > THR)) {
#pragma unroll
            for (int j = 0; j < 4; ++j) {
                float mx = fmaxf(s0[j], s1[j]);
                mx = fmaxf(mx, __shfl_xor(mx, 1));
                mx = fmaxf(mx, __shfl_xor(mx, 2));
                mx = fmaxf(mx, __shfl_xor(mx, 4));
                mx = fmaxf(mx, __shfl_xor(mx, 8));
                float mn = fmaxf(m[j], mx);
                float scale = __expf(m[j] - mn);
                m[j] = mn;
#pragma unroll
                for (int t = 0; t < 17; ++t) o[t][j] *= scale;
            }
        }
        // P -> LDS (wave-private; masked entries underflow to 0; pre-first-max
        // junk exp(0)=1 wiped by scale=0 at the row's first real max)
        ushort* Pw = Pl + (size_t)w * 16 * 36;
#pragma unroll
        for (int j = 0; j < 4; ++j) {
            Pw[(lk * 4 + j) * 36 + lr]      = f2bf(__expf(s0[j] - m[j]));
            Pw[(lk * 4 + j) * 36 + 16 + lr] = f2bf(__expf(s1[j] - m[j]));
        }
        asm volatile("s_waitcnt lgkmcnt(0)" ::: "memory");
        __builtin_amdgcn_sched_barrier(0);
        short8 pa = *reinterpret_cast<const short8*>(Pw + lr * 36 + lk * 8);
        // O += P @ V from LDS V tile
        const char* Vb = (const char*)(VlB + cur * (256 * 32));
        int vcp = lk ^ ((lr >> 2) & 3);
#pragma unroll
        for (int t = 0; t < 16; ++t) {
            short8 vf = *reinterpret_cast<const short8*>(Vb + ((t * 16 + lr) << 6) + (vcp << 4));
            o[t] = __builtin_amdgcn_mfma_f32_16x16x32_bf16(pa, vf, o[t], 0, 0, 0);
        }
        o[16] = __builtin_amdgcn_mfma_f32_16x16x32_bf16(pa, ones, o[16], 0, 0, 0);
        __syncthreads();   // drains vmcnt (staged tile ready) + LDS reads done
        cur ^= 1;
    }

    // ---- write split-K partials ----
    ushort* op = Opart + ((size_t)kq * NN + rw0) * DD;
#pragma unroll
    for (int t = 0; t < 16; ++t)
#pragma unroll
        for (int j = 0; j < 4; ++j)
            op[(size_t)(lk * 4 + j) * DD + t * 16 + lr] = f2bf(o[t][j]);
    if (lr == 0) {
#pragma unroll
        for (int j = 0; j < 4; ++j) {
            mpart[kq * NN + rw0 + lk * 4 + j] = m[j];
            lpart[kq * NN + rw0 + lk * 4 + j] = o[16][j];
        }
    }
}

// --- merge 8 split-K partials + CRF epilogue ---
__global__ __launch_bounds__(256) void k_merge8(const ushort* __restrict__ Opart,
                                                const float* __restrict__ mpart,
                                                const float* __restrict__ lpart,
                                                const float* __restrict__ Qo,
                                                float* __restrict__ dst) {
    int w = threadIdx.x >> 6;
    int lane = threadIdx.x & 63;
    int r0 = blockIdx.x * 32 + w * 8;
    for (int rr = 0; rr < 8; ++rr) {
        int r = r0 + rr;
        float mv[8], f[8];
        float M = -1e30f;
#pragma unroll
        for (int p = 0; p < 8; ++p) { mv[p] = mpart[p * NN + r]; M = fmaxf(M, mv[p]); }
        float L = 0.f;
#pragma unroll
        for (int p = 0; p < 8; ++p) { f[p] = __expf(mv[p] - M); L += f[p] * lpart[p * NN + r]; }
        float invL = 1.0f / L;
        int c = lane * 4;
        float a0 = 0.f, a1 = 0.f, a2 = 0.f, a3 = 0.f;
#pragma unroll
        for (int p = 0; p < 8; ++p) {
            ushort4 u = *reinterpret_cast<const ushort4*>(Opart + ((size_t)p * NN + r) * DD + c);
            a0 += f[p] * bf2f(u.x); a1 += f[p] * bf2f(u.y);
            a2 += f[p] * bf2f(u.z); a3 += f[p] * bf2f(u.w);
        }
        float4 qv = *reinterpret_cast<const float4*>(Qo + (size_t)r * DD + c);
        float4 ov;
        ov.x = (ALPHA * qv.x + a0 * invL) * (1.0f / (ALPHA + BETA));
        ov.y = (ALPHA * qv.y + a1 * invL) * (1.0f / (ALPHA + BETA));
        ov.z = (ALPHA * qv.z + a2 * invL) * (1.0f / (ALPHA + BETA));
        ov.w = (ALPHA * qv.w + a3 * invL) * (1.0f / (ALPHA + BETA));
        *reinterpret_cast<float4*>(dst + (size_t)r * DD + c) = ov;
    }
}

extern "C" void kernel_launch(void* const* d_in, const int* in_sizes, int n_in,
                              void* d_out, int out_size, void* d_ws, size_t ws_size,
                              hipStream_t stream) {
    const float* Q   = (const float*)d_in[0];
    const float* sim = (const float*)d_in[1];
    const float* W   = (const float*)d_in[2];
    const float* b   = (const float*)d_in[3];
    float* out = (float*)d_out;

    char* ws = (char*)d_ws;
    size_t off = 0;
    ushort* Hv   = (ushort*)(ws + off); off += (size_t)NN * DD * 2;
    ushort* HvtA = (ushort*)(ws + off); off += (size_t)NN * DD * 2;
    ushort* HvtB = (ushort*)(ws + off); off += (size_t)NN * DD * 2;
    ushort* Hp   = (ushort*)(ws + off); off += (size_t)NN * DD * 2;
    ushort* Wb   = (ushort*)(ws + off); off += (size_t)DD * DD * 2;
    unsigned* bits = (unsigned*)(ws + off); off += (size_t)NN * (NN / 32) * 4;
    float*  H1   = (float*)(ws + off);  off += (size_t)NN * DD * 4;
    ushort* Opart = (ushort*)(ws + off); off += (size_t)KQ * NN * DD * 2;
    float*  mpart = (float*)(ws + off);  off += (size_t)KQ * NN * 4;
    float*  lpart = (float*)(ws + off);  off += (size_t)KQ * NN * 4;

    (void)hipFuncSetAttribute((const void*)k_attn,
                              hipFuncAttributeMaxDynamicSharedMemorySize, SMEM_ATTN);

    k_wconv<<<DD * DD / 256, 256, 0, stream>>>(W, Wb);
    k_pack<<<NN, 256, 0, stream>>>(sim, bits);
    k_convert<<<(NN / 64) * (DD / 64), 256, 0, stream>>>(Q, Hv, HvtA);

    // iter 1: V = Q (HvtA)
    k_proj<<<NN / 32, 256, 0, stream>>>(Hv, Wb, b, Hp);
    k_attn<<<(NN / 64) * KQ, 256, SMEM_ATTN, stream>>>(Hp, HvtA, bits, Opart, mpart, lpart);
    k_merge8<<<NN / 32, 256, 0, stream>>>(Opart, mpart, lpart, Q, H1);
    k_convert<<<(NN / 64) * (DD / 64), 256, 0, stream>>>(H1, Hv, HvtB);

    // iter 2: V = H1 (HvtB)
    k_proj<<<NN / 32, 256, 0, stream>>>(Hv, Wb, b, Hp);
    k_attn<<<(NN / 64) * KQ, 256, SMEM_ATTN, stream>>>(Hp, HvtB, bits, Opart, mpart, lpart);
    k_merge8<<<NN / 32, 256, 0, stream>>>(Opart, mpart, lpart, Q, out);
}

// Round 9
// 359.919 us; speedup vs baseline: 4.4854x; 1.0567x over previous
//
#include <hip/hip_runtime.h>

#define NN 8192
#define DD 256
#define ALPHA 50.0f
#define BETA 1.0f
#define THR 10.0f
#define KQ 8                 // key splits
#define KEYS (NN / KQ)       // 1024 keys per split
#define STEPS (KEYS / 32)    // 32
#define QROWS 128            // q-rows per block (8 waves x 16)

typedef __attribute__((ext_vector_type(8))) short short8;
typedef __attribute__((ext_vector_type(4))) float f32x4;

static __device__ __forceinline__ ushort f2bf(float f) {
    union { float f; unsigned u; } v; v.f = f;
    unsigned u = v.u;
    return (ushort)((u + 0x7fffu + ((u >> 16) & 1u)) >> 16);
}
static __device__ __forceinline__ float bf2f(ushort u) {
    union { unsigned u; float f; } v; v.u = ((unsigned)u) << 16;
    return v.f;
}
static __device__ __forceinline__ void gl_lds16(const ushort* g, ushort* l) {
    __builtin_amdgcn_global_load_lds(
        (const __attribute__((address_space(1))) unsigned int*)g,
        (__attribute__((address_space(3))) unsigned int*)l, 16, 0, 0);
}

// --- W f32 -> bf16, once ---
__global__ void k_wconv(const float* __restrict__ W, ushort* __restrict__ Wb) {
    int i = blockIdx.x * 256 + threadIdx.x;
    Wb[i] = f2bf(W[i]);
}

// --- bitpack mask: bits[row][col/32]; float4 loads + LDS nibble assembly ---
__global__ __launch_bounds__(256) void k_pack(const float* __restrict__ sim,
                                              unsigned* __restrict__ bits) {
    __shared__ unsigned char nibs[256];
    int row = blockIdx.x;
    int tid = threadIdx.x;
    for (int p = 0; p < 8; ++p) {
        int col = p * 1024 + tid * 4;
        float4 v = *reinterpret_cast<const float4*>(sim + (size_t)row * NN + col);
        unsigned char nib = (unsigned char)((v.x != 0.f) | ((v.y != 0.f) << 1) |
                                            ((v.z != 0.f) << 2) | ((v.w != 0.f) << 3));
        nibs[tid] = nib;
        __syncthreads();
        if (tid < 32) {
            unsigned word = 0;
#pragma unroll
            for (int i = 0; i < 8; ++i) word |= ((unsigned)nibs[tid * 8 + i]) << (4 * i);
            bits[row * (NN / 32) + p * 32 + tid] = word;
        }
        __syncthreads();
    }
}

// --- H f32 -> Hv bf16 (row-major) and Hvt bf16 (transposed [D][N]) ---
__global__ __launch_bounds__(256) void k_convert(const float* __restrict__ H,
                                                 ushort* __restrict__ Hv,
                                                 ushort* __restrict__ Hvt) {
    __shared__ ushort T[64][72];
    int tile = blockIdx.x;
    int r0 = (tile >> 2) * 64;
    int c0 = (tile & 3) * 64;
    int tid = threadIdx.x;
    int tr = tid >> 4;
    int tc = (tid & 15) * 4;
    for (int i = 0; i < 4; ++i) {
        int r = tr + i * 16;
        float4 v = *reinterpret_cast<const float4*>(H + (size_t)(r0 + r) * DD + c0 + tc);
        ushort4 o;
        o.x = f2bf(v.x); o.y = f2bf(v.y); o.z = f2bf(v.z); o.w = f2bf(v.w);
        *reinterpret_cast<ushort4*>(Hv + (size_t)(r0 + r) * DD + c0 + tc) = o;
        T[tc + 0][r] = o.x; T[tc + 1][r] = o.y; T[tc + 2][r] = o.z; T[tc + 3][r] = o.w;
    }
    __syncthreads();
    for (int i = 0; i < 4; ++i) {
        int c = tr + i * 16;
        ushort4 o;
        o.x = T[c][tc + 0]; o.y = T[c][tc + 1]; o.z = T[c][tc + 2]; o.w = T[c][tc + 3];
        *reinterpret_cast<ushort4*>(Hvt + (size_t)(c0 + c) * NN + r0 + tc) = o;
    }
}

// --- Hp = bf16(Hv @ W^T + b) ---
__global__ __launch_bounds__(256) void k_proj(const ushort* __restrict__ Hv,
                                              const ushort* __restrict__ Wb,
                                              const float* __restrict__ b,
                                              ushort* __restrict__ Hp) {
    int w = threadIdx.x >> 6;
    int lane = threadIdx.x & 63;
    int row0 = (blockIdx.x >> 1) * 64 + w * 16;
    int ch = blockIdx.x & 1;
    int lr = lane & 15;
    int lk = lane >> 4;
    short8 af[8];
    for (int kk = 0; kk < 8; ++kk)
        af[kk] = *reinterpret_cast<const short8*>(Hv + (size_t)(row0 + lr) * DD + kk * 32 + lk * 8);
    for (int t = 0; t < 8; ++t) {
        f32x4 acc = {0.f, 0.f, 0.f, 0.f};
        int col = (ch * 8 + t) * 16 + lr;
        for (int kk = 0; kk < 8; ++kk) {
            short8 bf = *reinterpret_cast<const short8*>(Wb + (size_t)col * DD + kk * 32 + lk * 8);
            acc = __builtin_amdgcn_mfma_f32_16x16x32_bf16(af[kk], bf, acc, 0, 0, 0);
        }
        float bias = b[col];
        for (int j = 0; j < 4; ++j) {
            int row = row0 + lk * 4 + j;
            Hp[(size_t)row * DD + col] = f2bf(acc[j] + bias);
        }
    }
}

// --- fused masked flash attention, split-K partials, LDS-staged K/V ---
// grid = 512: kq = bid&7 (XCD-local 1024-key range), qt = bid>>3 (128 q-rows).
// 8 waves x 16 q-rows share one staged K/V tile (staging cost halved per q).
#define PSTR 40
#define SMEM_ATTN (2 * 32 * 256 * 2 + 2 * 256 * 32 * 2 + 8 * 16 * PSTR * 2)
__global__ __launch_bounds__(512) void k_attn(const ushort* __restrict__ Hp,
                                              const ushort* __restrict__ Hvt,
                                              const unsigned* __restrict__ bits,
                                              ushort* __restrict__ Opart,
                                              float* __restrict__ mpart,
                                              float* __restrict__ lpart) {
    extern __shared__ char smem[];
    ushort* KlB = (ushort*)smem;                  // 2 x [32][256] swizzled
    ushort* VlB = (ushort*)(smem + 32768);        // 2 x [256][32] swizzled
    ushort* Pl  = (ushort*)(smem + 65536);        // 8 x [16][PSTR]

    const int tid = threadIdx.x;
    const int w = tid >> 6;
    const int lane = tid & 63;
    const int lr = lane & 15;
    const int lk = lane >> 4;
    const int bid = blockIdx.x;
    const int kq = bid & 7;
    const int qt = bid >> 3;
    const int rw0 = qt * QROWS + w * 16;
    const int kstart = kq * KEYS;

    // 1024 16B-slots per tile, 512 threads -> 2 insts each
    auto stageK = [&](int buf, int kb) {
        const ushort* Kg = Hp + (size_t)kb * DD;
        ushort* base = KlB + buf * (32 * 256);
#pragma unroll
        for (int i = 0; i < 2; ++i) {
            int S = (w * 2 + i) * 64 + lane;
            int r = S >> 5, cp = S & 31;
            int cc = cp ^ (r & 7);
            gl_lds16(Kg + r * 256 + cc * 8, base + S * 8);
        }
    };
    auto stageV = [&](int buf, int kb) {
        ushort* base = VlB + buf * (256 * 32);
#pragma unroll
        for (int i = 0; i < 2; ++i) {
            int S = (w * 2 + i) * 64 + lane;
            int r = S >> 2, cp = S & 3;
            int cc = cp ^ ((r >> 2) & 3);
            gl_lds16(Hvt + (size_t)r * NN + kb + cc * 8, base + S * 8);
        }
    };

    short8 qf[8];
#pragma unroll
    for (int kk = 0; kk < 8; ++kk)
        qf[kk] = *reinterpret_cast<const short8*>(Hp + (size_t)(rw0 + lr) * DD + kk * 32 + lk * 8);

    f32x4 o[17];
#pragma unroll
    for (int t = 0; t < 17; ++t) o[t] = {0.f, 0.f, 0.f, 0.f};
    float m[4] = {-1e30f, -1e30f, -1e30f, -1e30f};

    short8 ones;
#pragma unroll
    for (int e = 0; e < 8; ++e) ones[e] = (short)0x3f80;  // bf16 1.0

    stageK(0, kstart);
    stageV(0, kstart);
    __syncthreads();

    const int rowbase = (rw0 + lk * 4) * (NN / 32);
    int cur = 0;
    for (int step = 0; step < STEPS; ++step) {
        const int kb = kstart + step * 32;
        if (step + 1 < STEPS) {
            stageK(cur ^ 1, kb + 32);
            stageV(cur ^ 1, kb + 32);
        }
        const int wi = kb >> 5;
        unsigned mwj[4];
#pragma unroll
        for (int j = 0; j < 4; ++j) mwj[j] = bits[rowbase + j * (NN / 32) + wi];

        // QK^T from LDS K tile (swizzled ds_read_b128)
        const char* Kb = (const char*)(KlB + cur * (32 * 256));
        f32x4 s0 = {0.f, 0.f, 0.f, 0.f}, s1 = {0.f, 0.f, 0.f, 0.f};
#pragma unroll
        for (int kk = 0; kk < 8; ++kk) {
            int cp = (kk * 4 + lk) ^ (lr & 7);
            short8 k0 = *reinterpret_cast<const short8*>(Kb + (lr << 9) + (cp << 4));
            short8 k1 = *reinterpret_cast<const short8*>(Kb + ((16 + lr) << 9) + (cp << 4));
            s0 = __builtin_amdgcn_mfma_f32_16x16x32_bf16(qf[kk], k0, s0, 0, 0, 0);
            s1 = __builtin_amdgcn_mfma_f32_16x16x32_bf16(qf[kk], k1, s1, 0, 0, 0);
        }
        // mask + defer-max
        float c = -1e30f;
#pragma unroll
        for (int j = 0; j < 4; ++j) {
            float a0 = ((mwj[j] >> lr) & 1u) ? s0[j] : -1e30f;
            float a1 = ((mwj[j] >> (lr + 16)) & 1u) ? s1[j] : -1e30f;
            s0[j] = a0; s1[j] = a1;
            c = fmaxf(c, fmaxf(a0, a1) - m[j]);
        }
        if (__any(c > THR)) {
#pragma unroll
            for (int j = 0; j < 4; ++j) {
                float mx = fmaxf(s0[j], s1[j]);
                mx = fmaxf(mx, __shfl_xor(mx, 1));
                mx = fmaxf(mx, __shfl_xor(mx, 2));
                mx = fmaxf(mx, __shfl_xor(mx, 4));
                mx = fmaxf(mx, __shfl_xor(mx, 8));
                float mn = fmaxf(m[j], mx);
                float scale = __expf(m[j] - mn);
                m[j] = mn;
#pragma unroll
                for (int t = 0; t < 17; ++t) o[t][j] *= scale;
            }
        }
        // P -> LDS (wave-private; masked entries underflow to 0; pre-first-max
        // junk exp(0)=1 wiped by scale=0 at the row's first real max)
        ushort* Pw = Pl + (size_t)w * 16 * PSTR;
#pragma unroll
        for (int j = 0; j < 4; ++j) {
            Pw[(lk * 4 + j) * PSTR + lr]      = f2bf(__expf(s0[j] - m[j]));
            Pw[(lk * 4 + j) * PSTR + 16 + lr] = f2bf(__expf(s1[j] - m[j]));
        }
        asm volatile("s_waitcnt lgkmcnt(0)" ::: "memory");
        __builtin_amdgcn_sched_barrier(0);
        short8 pa = *reinterpret_cast<const short8*>(Pw + lr * PSTR + lk * 8);
        // O += P @ V from LDS V tile
        const char* Vb = (const char*)(VlB + cur * (256 * 32));
        int vcp = lk ^ ((lr >> 2) & 3);
#pragma unroll
        for (int t = 0; t < 16; ++t) {
            short8 vf = *reinterpret_cast<const short8*>(Vb + ((t * 16 + lr) << 6) + (vcp << 4));
            o[t] = __builtin_amdgcn_mfma_f32_16x16x32_bf16(pa, vf, o[t], 0, 0, 0);
        }
        o[16] = __builtin_amdgcn_mfma_f32_16x16x32_bf16(pa, ones, o[16], 0, 0, 0);
        __syncthreads();   // drains vmcnt (staged tile ready) + LDS reads done
        cur ^= 1;
    }

    // ---- write split-K partials ----
    ushort* op = Opart + ((size_t)kq * NN + rw0) * DD;
#pragma unroll
    for (int t = 0; t < 16; ++t)
#pragma unroll
        for (int j = 0; j < 4; ++j)
            op[(size_t)(lk * 4 + j) * DD + t * 16 + lr] = f2bf(o[t][j]);
    if (lr == 0) {
#pragma unroll
        for (int j = 0; j < 4; ++j) {
            mpart[kq * NN + rw0 + lk * 4 + j] = m[j];
            lpart[kq * NN + rw0 + lk * 4 + j] = o[16][j];
        }
    }
}

// --- merge 8 split-K partials + CRF epilogue ---
__global__ __launch_bounds__(256) void k_merge8(const ushort* __restrict__ Opart,
                                                const float* __restrict__ mpart,
                                                const float* __restrict__ lpart,
                                                const float* __restrict__ Qo,
                                                float* __restrict__ dst) {
    int w = threadIdx.x >> 6;
    int lane = threadIdx.x & 63;
    int r0 = blockIdx.x * 32 + w * 8;
    for (int rr = 0; rr < 8; ++rr) {
        int r = r0 + rr;
        float mv[8], f[8];
        float M = -1e30f;
#pragma unroll
        for (int p = 0; p < 8; ++p) { mv[p] = mpart[p * NN + r]; M = fmaxf(M, mv[p]); }
        float L = 0.f;
#pragma unroll
        for (int p = 0; p < 8; ++p) { f[p] = __expf(mv[p] - M); L += f[p] * lpart[p * NN + r]; }
        float invL = 1.0f / L;
        int c = lane * 4;
        float a0 = 0.f, a1 = 0.f, a2 = 0.f, a3 = 0.f;
#pragma unroll
        for (int p = 0; p < 8; ++p) {
            ushort4 u = *reinterpret_cast<const ushort4*>(Opart + ((size_t)p * NN + r) * DD + c);
            a0 += f[p] * bf2f(u.x); a1 += f[p] * bf2f(u.y);
            a2 += f[p] * bf2f(u.z); a3 += f[p] * bf2f(u.w);
        }
        float4 qv = *reinterpret_cast<const float4*>(Qo + (size_t)r * DD + c);
        float4 ov;
        ov.x = (ALPHA * qv.x + a0 * invL) * (1.0f / (ALPHA + BETA));
        ov.y = (ALPHA * qv.y + a1 * invL) * (1.0f / (ALPHA + BETA));
        ov.z = (ALPHA * qv.z + a2 * invL) * (1.0f / (ALPHA + BETA));
        ov.w = (ALPHA * qv.w + a3 * invL) * (1.0f / (ALPHA + BETA));
        *reinterpret_cast<float4*>(dst + (size_t)r * DD + c) = ov;
    }
}

extern "C" void kernel_launch(void* const* d_in, const int* in_sizes, int n_in,
                              void* d_out, int out_size, void* d_ws, size_t ws_size,
                              hipStream_t stream) {
    const float* Q   = (const float*)d_in[0];
    const float* sim = (const float*)d_in[1];
    const float* W   = (const float*)d_in[2];
    const float* b   = (const float*)d_in[3];
    float* out = (float*)d_out;

    char* ws = (char*)d_ws;
    size_t off = 0;
    ushort* Hv   = (ushort*)(ws + off); off += (size_t)NN * DD * 2;
    ushort* HvtA = (ushort*)(ws + off); off += (size_t)NN * DD * 2;
    ushort* HvtB = (ushort*)(ws + off); off += (size_t)NN * DD * 2;
    ushort* Hp   = (ushort*)(ws + off); off += (size_t)NN * DD * 2;
    ushort* Wb   = (ushort*)(ws + off); off += (size_t)DD * DD * 2;
    unsigned* bits = (unsigned*)(ws + off); off += (size_t)NN * (NN / 32) * 4;
    float*  H1   = (float*)(ws + off);  off += (size_t)NN * DD * 4;
    ushort* Opart = (ushort*)(ws + off); off += (size_t)KQ * NN * DD * 2;
    float*  mpart = (float*)(ws + off);  off += (size_t)KQ * NN * 4;
    float*  lpart = (float*)(ws + off);  off += (size_t)KQ * NN * 4;

    (void)hipFuncSetAttribute((const void*)k_attn,
                              hipFuncAttributeMaxDynamicSharedMemorySize, SMEM_ATTN);

    k_wconv<<<DD * DD / 256, 256, 0, stream>>>(W, Wb);
    k_pack<<<NN, 256, 0, stream>>>(sim, bits);
    k_convert<<<(NN / 64) * (DD / 64), 256, 0, stream>>>(Q, Hv, HvtA);

    // iter 1: V = Q (HvtA)
    k_proj<<<NN / 32, 256, 0, stream>>>(Hv, Wb, b, Hp);
    k_attn<<<(NN / QROWS) * KQ, 512, SMEM_ATTN, stream>>>(Hp, HvtA, bits, Opart, mpart, lpart);
    k_merge8<<<NN / 32, 256, 0, stream>>>(Opart, mpart, lpart, Q, H1);
    k_convert<<<(NN / 64) * (DD / 64), 256, 0, stream>>>(H1, Hv, HvtB);

    // iter 2: V = H1 (HvtB)
    k_proj<<<NN / 32, 256, 0, stream>>>(Hv, Wb, b, Hp);
    k_attn<<<(NN / QROWS) * KQ, 512, SMEM_ATTN, stream>>>(Hp, HvtB, bits, Opart, mpart, lpart);
    k_merge8<<<NN / 32, 256, 0, stream>>>(Opart, mpart, lpart, Q, out);
}